// Round 2
// baseline (261.173 us; speedup 1.0000x reference)
//
#include <hip/hip_runtime.h>
#include <hip/hip_bf16.h>

#define NB 2
#define L_SEQ 2048
#define NH 16
#define DKH 64
#define DMODEL 1024
#define MROWS (NB * L_SEQ)          // 4096
#define QSCALE 0.18033688f          // 0.125 * log2(e), folded into Q
#define DD (DMODEL * DMODEL)

typedef __attribute__((ext_vector_type(8))) short short8;
typedef __attribute__((ext_vector_type(4))) float f32x4;

static __device__ __forceinline__ unsigned short f2bf(float f) {
    unsigned u = __float_as_uint(f);
    u += 0x7fffu + ((u >> 16) & 1u);   // RTN-even
    return (unsigned short)(u >> 16);
}

static __device__ __forceinline__ float fexp2(float x) {
#if __has_builtin(__builtin_amdgcn_exp2f)
    return __builtin_amdgcn_exp2f(x);
#else
    return __expf(x * 0.6931471806f);
#endif
}

static __device__ __forceinline__ unsigned pk_bf16(float a, float b) {
    __hip_bfloat162 h = __float22bfloat162_rn(make_float2(a, b));
    return *reinterpret_cast<unsigned*>(&h);
}

static __device__ __forceinline__ void gll16(const void* g, void* l) {
    __builtin_amdgcn_global_load_lds(
        (const __attribute__((address_space(1))) void*)g,
        (__attribute__((address_space(3))) void*)l, 16, 0, 0);
}

// ---------------------------------------------------------------------------
// prep: fused cast3 + castWt + maskbits (grid-strided mask branch)
// ---------------------------------------------------------------------------
__global__ __launch_bounds__(256)
void prep(const float* __restrict__ Xq, const float* __restrict__ Xk,
          const float* __restrict__ Xv, const float* __restrict__ w0,
          const float* __restrict__ w1, const float* __restrict__ w2,
          const float* __restrict__ w3, const int* __restrict__ mask,
          unsigned short* __restrict__ XB, unsigned short* __restrict__ WtB,
          unsigned long long* __restrict__ MWT)
{
    __shared__ float ts[32][33];
    const int bx = blockIdx.x;
    const int t  = threadIdx.x;

    if (bx < 12288) {
        const int z = bx >> 12;
        const float* src = (z == 0) ? Xq : (z == 1) ? Xk : Xv;
        const size_t i4 = (size_t)(bx & 4095) * 256 + t;
        float4 v = ((const float4*)src)[i4];
        ushort4 o;
        o.x = f2bf(v.x); o.y = f2bf(v.y); o.z = f2bf(v.z); o.w = f2bf(v.w);
        ((ushort4*)(XB + (size_t)z * 4194304))[i4] = o;
    } else if (bx < 16384) {
        const int idx = bx - 12288;
        const int z   = idx >> 10;
        const int rem = idx & 1023;
        const float* W = (z == 0) ? w0 : (z == 1) ? w1 : (z == 2) ? w2 : w3;
        unsigned short* Wt = WtB + (size_t)z * DD;
        const int n0 = (rem & 31) * 32;
        const int k0 = (rem >> 5) * 32;
        const int r  = t >> 3;
        const int c  = (t & 7) * 4;
        float4 v = *(const float4*)&W[(size_t)(k0 + r) * DMODEL + n0 + c];
        ts[r][c + 0] = v.x; ts[r][c + 1] = v.y;
        ts[r][c + 2] = v.z; ts[r][c + 3] = v.w;
        __syncthreads();
        ushort4 o;
        o.x = f2bf(ts[c + 0][r]); o.y = f2bf(ts[c + 1][r]);
        o.z = f2bf(ts[c + 2][r]); o.w = f2bf(ts[c + 3][r]);
        *(ushort4*)&Wt[(size_t)(n0 + r) * DMODEL + k0 + c] = o;
    } else {
        const int lane = t & 63;
        const size_t wbase = (size_t)(bx - 16384) * 4 + (t >> 6);
#pragma unroll
        for (int it = 0; it < 8; ++it) {
            const size_t wid = wbase + (size_t)it * 16384;   // < 131072
            const int mv = mask[wid * 64 + lane];
            const unsigned long long bits = __ballot(mv != 0);
            if (lane == 0) {
                const int b   = (int)(wid >> 16);
                const int rem = (int)(wid & 65535);
                const int row = rem >> 5;
                const int wd  = rem & 31;
                MWT[((size_t)b * 32 + wd) * L_SEQ + row] = bits;
            }
        }
    }
}

// ---------------------------------------------------------------------------
// QKV GEMM (unchanged)
// ---------------------------------------------------------------------------
__global__ __launch_bounds__(256)
void gemm_qkv(const unsigned short* __restrict__ XB,
              const unsigned short* __restrict__ WtB,
              unsigned short* __restrict__ QKV)
{
    __shared__ __align__(16) unsigned short SMEM[16384];   // 32 KB

    const int t    = threadIdx.x;
    const int w    = t >> 6;
    const int lane = t & 63;

    const int bid   = blockIdx.x;
    const int xcd   = bid & 7;
    const int idx   = bid >> 3;           // 0..95
    const int pair  = xcd * 12 + (idx >> 3);
    const int n0    = (idx & 7) * 128;
    const int m0    = (pair & 31) * 128;
    const int z     = pair >> 5;

    const unsigned short* A = XB  + (size_t)z * ((size_t)MROWS * DMODEL);
    const unsigned short* B = WtB + (size_t)z * DD;

    const int srow = lane >> 2;
    const int sc4  = (lane & 3) ^ (srow & 3);

    const unsigned short* ag[2];
    const unsigned short* bg[2];
    int lao[2], lbo[2];
#pragma unroll
    for (int g = 0; g < 2; ++g) {
        const int R = w * 32 + g * 16;
        ag[g] = A + (size_t)(m0 + R + srow) * DMODEL + sc4 * 8;
        bg[g] = B + (size_t)(n0 + R + srow) * DMODEL + sc4 * 8;
        lao[g] = R * 32;
        lbo[g] = R * 32;
    }

    const int ml = lane & 15;
    const int q  = lane >> 4;
    const int wm = (w >> 1) * 64;
    const int wn = (w & 1) * 64;

    const f32x4 z4 = {0.f, 0.f, 0.f, 0.f};
    f32x4 acc[4][4];
#pragma unroll
    for (int i = 0; i < 4; ++i)
#pragma unroll
        for (int j = 0; j < 4; ++j) acc[i][j] = z4;

#pragma unroll
    for (int g = 0; g < 2; ++g) {
        gll16(ag[g], &SMEM[lao[g]]);
        gll16(bg[g], &SMEM[8192 + lbo[g]]);
    }

    for (int j = 0; j < 32; ++j) {
        const int cur = j & 1;
        __syncthreads();
        if (j < 31) {
            const int kt = (j + 1) * 32;
            const int nb = (cur ^ 1) * 4096;
#pragma unroll
            for (int g = 0; g < 2; ++g) {
                gll16(ag[g] + kt, &SMEM[nb + lao[g]]);
                gll16(bg[g] + kt, &SMEM[8192 + nb + lbo[g]]);
            }
        }
        const unsigned short* As = &SMEM[cur * 4096];
        const unsigned short* Bs = &SMEM[8192 + cur * 4096];
        short8 av[4], bv[4];
#pragma unroll
        for (int mt = 0; mt < 4; ++mt)
            av[mt] = *(const short8*)
                &As[(wm + mt * 16 + ml) * 32 + ((q ^ (ml & 3)) * 8)];
#pragma unroll
        for (int nt = 0; nt < 4; ++nt)
            bv[nt] = *(const short8*)
                &Bs[(wn + nt * 16 + ml) * 32 + ((q ^ (ml & 3)) * 8)];
#pragma unroll
        for (int mt = 0; mt < 4; ++mt)
#pragma unroll
            for (int nt = 0; nt < 4; ++nt)
                acc[mt][nt] = __builtin_amdgcn_mfma_f32_16x16x32_bf16(
                    av[mt], bv[nt], acc[mt][nt], 0, 0, 0);
    }

    unsigned short* O = QKV + (size_t)z * ((size_t)MROWS * DMODEL);
    __syncthreads();                     // K-loop reads done; reuse SMEM
    unsigned short* Ts = SMEM;           // [128][128] bf16 = 32 KB

    if (z == 2) {
        // V^T: stage transposed [tcol=n][trow=m] (swizzled), wide stores
#pragma unroll
        for (int mt = 0; mt < 4; ++mt) {
            const int trow0 = wm + mt * 16 + q * 4;
            const int ch    = trow0 >> 3;
#pragma unroll
            for (int nt = 0; nt < 4; ++nt) {
                const int tcol = wn + nt * 16 + ml;
                const int pc   = (ch & 8) | ((ch & 7) ^ (tcol & 7));
                ushort4 pv;
                pv.x = f2bf(acc[mt][nt][0]); pv.y = f2bf(acc[mt][nt][1]);
                pv.z = f2bf(acc[mt][nt][2]); pv.w = f2bf(acc[mt][nt][3]);
                *(ushort4*)&Ts[tcol * 128 + pc * 8 + (trow0 & 7)] = pv;
            }
        }
        __syncthreads();
        const int bb = m0 >> 11;
        const int l0 = (m0 & (L_SEQ - 1)) + (t & 15) * 8;
        const int cr = t & 15;
#pragma unroll
        for (int it = 0; it < 8; ++it) {
            const int tcol = (t >> 4) + 16 * it;
            const int pc   = (cr & 8) | ((cr & 7) ^ (tcol & 7));
            short8 vv = *(const short8*)&Ts[tcol * 128 + pc * 8];
            const int n  = n0 + tcol;
            const int hh = n >> 6;
            const int dk = n & (DKH - 1);
            *(short8*)&O[((size_t)(bb * NH + hh) * DKH + dk) * L_SEQ + l0] = vv;
        }
    } else {
        // Q/K: stage untransposed [m][n], then short8 stores along dk
        const float qs = (z == 0) ? QSCALE : 1.0f;
#pragma unroll
        for (int mt = 0; mt < 4; ++mt) {
            const int row0 = wm + mt * 16 + q * 4;
#pragma unroll
            for (int nt = 0; nt < 4; ++nt) {
                const int col = wn + nt * 16 + ml;
#pragma unroll
                for (int r = 0; r < 4; ++r)
                    Ts[(row0 + r) * 128 + col] = f2bf(acc[mt][nt][r] * qs);
            }
        }
        __syncthreads();
        const int mloc = t >> 3;              // 0..31 (+32*pass)
        const int c0   = t & 7;               // chunk 0..7 (+8*half)
#pragma unroll
        for (int pass = 0; pass < 4; ++pass) {
#pragma unroll
            for (int half = 0; half < 2; ++half) {
                const int m = mloc + 32 * pass;
                const int c = c0 + 8 * half;
                short8 v = *(const short8*)&Ts[m * 128 + c * 8];
                const int row = m0 + m;
                const int bb  = row >> 11;
                const int l   = row & (L_SEQ - 1);
                const int n   = n0 + c * 8;
                const int hh  = n >> 6;
                const int dk  = n & (DKH - 1);
                *(short8*)&O[(((size_t)(bb * NH + hh) * L_SEQ + l) << 6) + dk] = v;
            }
        }
    }
}

// ---------------------------------------------------------------------------
// Output GEMM (unchanged)
// ---------------------------------------------------------------------------
__global__ __launch_bounds__(256)
void gemm_out(const unsigned short* __restrict__ OB,
              const unsigned short* __restrict__ Wt,
              float* __restrict__ out)
{
    __shared__ __align__(16) unsigned short As[2][2048];
    __shared__ __align__(16) unsigned short Bs[2][4096];

    const int t    = threadIdx.x;
    const int w    = t >> 6;
    const int lane = t & 63;

    const int bid = blockIdx.x;
    const int xcd = bid & 7;
    const int idx = bid >> 3;             // 0..63
    const int n0  = (idx & 7) * 128;
    const int m0  = (xcd * 8 + (idx >> 3)) * 64;

    const int srow = lane >> 2;
    const int sc4  = (lane & 3) ^ (srow & 3);

    const unsigned short* ag =
        OB + (size_t)(m0 + w * 16 + srow) * DMODEL + sc4 * 8;
    const unsigned short* bg[2];
    int lbo[2];
#pragma unroll
    for (int g = 0; g < 2; ++g) {
        const int R = w * 32 + g * 16;
        bg[g] = Wt + (size_t)(n0 + R + srow) * DMODEL + sc4 * 8;
        lbo[g] = R * 32;
    }
    const int lao = (w * 16) * 32;

    const int ml = lane & 15;
    const int q  = lane >> 4;
    const int wm = (w >> 1) * 32;
    const int wn = (w & 1) * 64;

    const f32x4 z4 = {0.f, 0.f, 0.f, 0.f};
    f32x4 acc[2][4];
#pragma unroll
    for (int i = 0; i < 2; ++i)
#pragma unroll
        for (int j = 0; j < 4; ++j) acc[i][j] = z4;

    gll16(ag, &As[0][lao]);
#pragma unroll
    for (int g = 0; g < 2; ++g) gll16(bg[g], &Bs[0][lbo[g]]);

    for (int j = 0; j < 32; ++j) {
        const int cur = j & 1;
        __syncthreads();
        if (j < 31) {
            const int kt = (j + 1) * 32;
            gll16(ag + kt, &As[cur ^ 1][lao]);
#pragma unroll
            for (int g = 0; g < 2; ++g)
                gll16(bg[g] + kt, &Bs[cur ^ 1][lbo[g]]);
        }
        short8 av[2], bv[4];
#pragma unroll
        for (int mt = 0; mt < 2; ++mt)
            av[mt] = *(const short8*)
                &As[cur][(wm + mt * 16 + ml) * 32 + ((q ^ (ml & 3)) * 8)];
#pragma unroll
        for (int nt = 0; nt < 4; ++nt)
            bv[nt] = *(const short8*)
                &Bs[cur][(wn + nt * 16 + ml) * 32 + ((q ^ (ml & 3)) * 8)];
#pragma unroll
        for (int mt = 0; mt < 2; ++mt)
#pragma unroll
            for (int nt = 0; nt < 4; ++nt)
                acc[mt][nt] = __builtin_amdgcn_mfma_f32_16x16x32_bf16(
                    av[mt], bv[nt], acc[mt][nt], 0, 0, 0);
    }

#pragma unroll
    for (int mt = 0; mt < 2; ++mt) {
        const int gr0 = m0 + wm + mt * 16 + q * 4;
#pragma unroll
        for (int nt = 0; nt < 4; ++nt) {
            const int col = n0 + wn + nt * 16 + ml;
#pragma unroll
            for (int r = 0; r < 4; ++r)
                out[(size_t)(gr0 + r) * DMODEL + col] = acc[mt][nt][r];
        }
    }
}

// ---------------------------------------------------------------------------
// MFMA flash attention — Q-block 128 retile (4 waves x 32 q-rows):
// K/V fragment reads amortized over 2 q-groups (qn) -> LDS read traffic per
// unit compute ~halved (LDS-BW was the bottleneck: ~3.3 GB at 85 B/cyc/CU
// ~= the whole 70 us). Double-buffered K/V/Msk in LDS -> ONE barrier per
// iteration; T14 reg-staging kept (loads issued one full iter ahead).
// Grid 512 (2 blocks/CU), LDS 50 KB.
// ---------------------------------------------------------------------------
__global__ __launch_bounds__(256, 2)
void attn_mfma(const unsigned short* __restrict__ Qb,
               const unsigned short* __restrict__ Kb,
               const unsigned short* __restrict__ Vtb,
               const unsigned long long* __restrict__ MWT,
               unsigned short* __restrict__ OB)
{
    __shared__ __align__(16) unsigned short Ks[2][64 * 64];    // 16 KB
    __shared__ __align__(16) unsigned short Vts[2][64 * 64];   // 16 KB
    __shared__ __align__(16) unsigned short Ps[4][32 * 64];    // 16 KB
    __shared__ __align__(16) unsigned long long MskL[2][128];  //  2 KB

    const int t    = threadIdx.x;
    const int w    = t >> 6;
    const int lane = t & 63;
    const int ml   = lane & 15;
    const int quad = lane >> 4;

    // 512 blocks: xcd = bid&7; 4 (b,h) pairs per XCD x 16 q-tiles
    const int bid = blockIdx.x;
    const int xcd = bid & 7;
    const int idx = bid >> 3;              // 0..63
    const int p   = xcd * 4 + (idx >> 4);  // (b,h) 0..31
    const int jq  = idx & 15;
    const int h   = p & 15;
    const int b   = p >> 4;
    const int q0  = jq * 128;

    const size_t hoff = (size_t)(b * NH + h) * L_SEQ * DKH;
    const unsigned short* Qh  = Qb  + hoff;
    const unsigned short* Kh  = Kb  + hoff;
    const unsigned short* Vth = Vtb + hoff;     // [64][L_SEQ]

    const int srow = lane >> 3;
    const int sc   = (lane & 7) ^ srow;

    // ---- stage Q (128x64) into the Ks region (16 KB overlay) ----
    unsigned short* QL = &Ks[0][0];
#pragma unroll
    for (int g = 0; g < 4; ++g)
        gll16(Qh + (size_t)(q0 + w * 32 + g * 8 + srow) * DKH + sc * 8,
              &QL[(w * 32 + g * 8) * 64]);

    // ---- K/V tile 0 into regs (overlaps Q staging) ----
    const unsigned short* kg0 = Kh + (size_t)(w * 16 + srow) * DKH + sc * 8;
    const unsigned short* kg1 = Kh + (size_t)(w * 16 + 8 + srow) * DKH + sc * 8;
    const unsigned short* vg0 = Vth + (size_t)(w * 16 + srow) * L_SEQ + sc * 8;
    const unsigned short* vg1 = Vth + (size_t)(w * 16 + 8 + srow) * L_SEQ + sc * 8;

    short8 kr0 = *(const short8*)kg0;  kg0 += 64 * DKH;
    short8 kr1 = *(const short8*)kg1;  kg1 += 64 * DKH;
    short8 vr0 = *(const short8*)vg0;  vg0 += 64;
    short8 vr1 = *(const short8*)vg1;  vg1 += 64;

    const unsigned long long* mg = MWT + (size_t)b * 32 * L_SEQ + q0 + t;
    unsigned long long m_pf = 0;
    if (t < 128) m_pf = mg[0];

    __syncthreads();                       // Q visible (vmcnt drained)

    short8 qf[2][2];
#pragma unroll
    for (int qn = 0; qn < 2; ++qn)
#pragma unroll
        for (int s = 0; s < 2; ++s)
            qf[qn][s] = *(const short8*)
                &QL[(w * 32 + qn * 16 + ml) * 64 +
                    (((s * 4 + quad) ^ (ml & 7)) * 8)];

    __syncthreads();                       // all waves read Q; Ks reusable

    // ---- write tile 0 -> buf0; issue tile 1 ----
    *(short8*)&Ks[0][(w * 16) * 64 + lane * 8]      = kr0;
    *(short8*)&Ks[0][(w * 16 + 8) * 64 + lane * 8]  = kr1;
    *(short8*)&Vts[0][(w * 16) * 64 + lane * 8]     = vr0;
    *(short8*)&Vts[0][(w * 16 + 8) * 64 + lane * 8] = vr1;
    if (t < 128) MskL[0][t] = m_pf;

    kr0 = *(const short8*)kg0;  kg0 += 64 * DKH;
    kr1 = *(const short8*)kg1;  kg1 += 64 * DKH;
    vr0 = *(const short8*)vg0;  vg0 += 64;
    vr1 = *(const short8*)vg1;  vg1 += 64;
    if (t < 128) m_pf = mg[L_SEQ];

    f32x4 oacc[2][4];
    const f32x4 z4 = {0.f, 0.f, 0.f, 0.f};
#pragma unroll
    for (int qn = 0; qn < 2; ++qn)
#pragma unroll
        for (int dt = 0; dt < 4; ++dt) oacc[qn][dt] = z4;
    float l_i[2] = {0.f, 0.f};

    __syncthreads();                       // tile 0 visible

    for (int j = 0; j < 32; ++j) {
        const int cur = j & 1;
        if (j < 31) {
            const int nxt = cur ^ 1;
            // write tile j+1 (regs issued at iter j-1; latency hidden)
            *(short8*)&Ks[nxt][(w * 16) * 64 + lane * 8]      = kr0;
            *(short8*)&Ks[nxt][(w * 16 + 8) * 64 + lane * 8]  = kr1;
            *(short8*)&Vts[nxt][(w * 16) * 64 + lane * 8]     = vr0;
            *(short8*)&Vts[nxt][(w * 16 + 8) * 64 + lane * 8] = vr1;
            if (t < 128) MskL[nxt][t] = m_pf;
            if (j < 30) {
                // issue tile j+2 loads; drain at iter j+1's ds_write
                kr0 = *(const short8*)kg0;  kg0 += 64 * DKH;
                kr1 = *(const short8*)kg1;  kg1 += 64 * DKH;
                vr0 = *(const short8*)vg0;  vg0 += 64;
                vr1 = *(const short8*)vg1;  vg1 += 64;
                if (t < 128) m_pf = mg[(size_t)(j + 2) * L_SEQ];
            }
        }

        // ---- QK^T: K fragments shared across both q-groups ----
        f32x4 sacc[2][4];
#pragma unroll
        for (int qn = 0; qn < 2; ++qn)
#pragma unroll
            for (int kt = 0; kt < 4; ++kt) sacc[qn][kt] = z4;
#pragma unroll
        for (int s = 0; s < 2; ++s) {
            short8 kf[4];
#pragma unroll
            for (int kt = 0; kt < 4; ++kt)
                kf[kt] = *(const short8*)
                    &Ks[cur][(kt * 16 + ml) * 64 +
                             (((s * 4 + quad) ^ (ml & 7)) * 8)];
#pragma unroll
            for (int qn = 0; qn < 2; ++qn)
#pragma unroll
                for (int kt = 0; kt < 4; ++kt)
                    sacc[qn][kt] = __builtin_amdgcn_mfma_f32_16x16x32_bf16(
                        kf[kt], qf[qn][s], sacc[qn][kt], 0, 0, 0);
        }

        // ---- masked softmax numerators for both q-groups ----
#pragma unroll
        for (int qn = 0; qn < 2; ++qn) {
            const unsigned long long wq =
                MskL[cur][w * 32 + qn * 16 + ml] >> (quad * 4);
            const unsigned mlo = (unsigned)wq;
            const unsigned mhi = (unsigned)(wq >> 32);
            float rs = 0.f;
            float pr[4][4];
#pragma unroll
            for (int kt = 0; kt < 4; ++kt) {
                const unsigned word = (kt < 2) ? mlo : mhi;
                const int base = (kt & 1) * 16;
#pragma unroll
                for (int r = 0; r < 4; ++r) {
                    const float mf = (float)((word >> (base + r)) & 1u);
                    const float e  = fexp2(sacc[qn][kt][r] * mf);
                    pr[kt][r] = e;
                    rs += e;
                }
            }
            rs += __shfl_xor(rs, 16);
            rs += __shfl_xor(rs, 32);
            l_i[qn] += rs;
#pragma unroll
            for (int kt = 0; kt < 4; ++kt) {
                uint2 pk;
                pk.x = pk_bf16(pr[kt][0], pr[kt][1]);
                pk.y = pk_bf16(pr[kt][2], pr[kt][3]);
                const int cp = (kt * 2 + (quad >> 1)) ^ (ml & 7);
                *(uint2*)&Ps[w][(qn * 16 + ml) * 64 + cp * 8 + (quad & 1) * 4] = pk;
            }
        }

        // ---- PV: V fragments shared across both q-groups ----
#pragma unroll
        for (int s = 0; s < 2; ++s) {
            short8 vf[4];
#pragma unroll
            for (int dt = 0; dt < 4; ++dt)
                vf[dt] = *(const short8*)
                    &Vts[cur][(dt * 16 + ml) * 64 +
                              (((s * 4 + quad) ^ (ml & 7)) * 8)];
#pragma unroll
            for (int qn = 0; qn < 2; ++qn) {
                const short8 pf = *(const short8*)
                    &Ps[w][(qn * 16 + ml) * 64 +
                           (((s * 4 + quad) ^ (ml & 7)) * 8)];
#pragma unroll
                for (int dt = 0; dt < 4; ++dt)
                    oacc[qn][dt] = __builtin_amdgcn_mfma_f32_16x16x32_bf16(
                        vf[dt], pf, oacc[qn][dt], 0, 0, 0);
            }
        }

        __syncthreads();                   // single barrier per iteration
    }

#pragma unroll
    for (int qn = 0; qn < 2; ++qn) {
        const float inv = 1.0f / l_i[qn];
        const int qrow = q0 + w * 32 + qn * 16 + ml;
#pragma unroll
        for (int dt = 0; dt < 4; ++dt) {
            ushort4 o4;
            o4.x = f2bf(oacc[qn][dt][0] * inv);
            o4.y = f2bf(oacc[qn][dt][1] * inv);
            o4.z = f2bf(oacc[qn][dt][2] * inv);
            o4.w = f2bf(oacc[qn][dt][3] * inv);
            *(ushort4*)&OB[(size_t)(b * L_SEQ + qrow) * DMODEL + h * DKH +
                           dt * 16 + quad * 4] = o4;
        }
    }
}

// ---------------------------------------------------------------------------
extern "C" void kernel_launch(void* const* d_in, const int* in_sizes, int n_in,
                              void* d_out, int out_size, void* d_ws, size_t ws_size,
                              hipStream_t stream)
{
    (void)in_sizes; (void)n_in; (void)out_size; (void)ws_size;

    const float* Xq   = (const float*)d_in[0];
    const float* Xk   = (const float*)d_in[1];
    const float* Xv   = (const float*)d_in[2];
    const float* Wq   = (const float*)d_in[3];
    const float* Wk   = (const float*)d_in[4];
    const float* Wv   = (const float*)d_in[5];
    const float* Wo   = (const float*)d_in[6];
    const int*   mask = (const int*)d_in[7];
    float* out = (float*)d_out;

    char* base = (char*)d_ws;
    unsigned short*     XB  = (unsigned short*)base;                 // 24 MB
    unsigned short*     WtB = (unsigned short*)(base + (24u << 20)); //  8 MB
    unsigned short*     QKV = (unsigned short*)(base + (32u << 20)); // 24 MB
    unsigned short*     OB  = (unsigned short*)(base + (56u << 20)); //  8 MB
    unsigned long long* MWT = (unsigned long long*)(base + (64u << 20)); // 1 MB

    const size_t tsz = (size_t)MROWS * DMODEL;   // 4,194,304

    prep<<<dim3(20480), 256, 0, stream>>>(
        Xq, Xk, Xv, Wq, Wk, Wv, Wo, mask, XB, WtB, MWT);

    gemm_qkv<<<dim3(768), 256, 0, stream>>>(XB, WtB, QKV);

    attn_mfma<<<dim3(512), 256, 0, stream>>>(
        QKV, QKV + tsz, QKV + 2 * tsz, MWT, OB);

    gemm_out<<<dim3(512), 256, 0, stream>>>(OB, WtB + 3 * (size_t)DD, out);
}

// Round 3
// 247.804 us; speedup vs baseline: 1.0540x; 1.0540x over previous
//
#include <hip/hip_runtime.h>
#include <hip/hip_bf16.h>

#define NB 2
#define L_SEQ 2048
#define NH 16
#define DKH 64
#define DMODEL 1024
#define MROWS (NB * L_SEQ)          // 4096
#define QSCALE 0.18033688f          // 0.125 * log2(e), folded into Q
#define DD (DMODEL * DMODEL)

typedef __attribute__((ext_vector_type(8))) short short8;
typedef __attribute__((ext_vector_type(4))) float f32x4;

static __device__ __forceinline__ unsigned short f2bf(float f) {
    unsigned u = __float_as_uint(f);
    u += 0x7fffu + ((u >> 16) & 1u);   // RTN-even
    return (unsigned short)(u >> 16);
}

static __device__ __forceinline__ float fexp2(float x) {
#if __has_builtin(__builtin_amdgcn_exp2f)
    return __builtin_amdgcn_exp2f(x);
#else
    return __expf(x * 0.6931471806f);
#endif
}

static __device__ __forceinline__ unsigned pk_bf16(float a, float b) {
    __hip_bfloat162 h = __float22bfloat162_rn(make_float2(a, b));
    return *reinterpret_cast<unsigned*>(&h);
}

static __device__ __forceinline__ void gll16(const void* g, void* l) {
    __builtin_amdgcn_global_load_lds(
        (const __attribute__((address_space(1))) void*)g,
        (__attribute__((address_space(3))) void*)l, 16, 0, 0);
}

// ---------------------------------------------------------------------------
// prep: fused cast3 + castWt + maskbits (grid-strided mask branch)
// ---------------------------------------------------------------------------
__global__ __launch_bounds__(256)
void prep(const float* __restrict__ Xq, const float* __restrict__ Xk,
          const float* __restrict__ Xv, const float* __restrict__ w0,
          const float* __restrict__ w1, const float* __restrict__ w2,
          const float* __restrict__ w3, const int* __restrict__ mask,
          unsigned short* __restrict__ XB, unsigned short* __restrict__ WtB,
          unsigned long long* __restrict__ MWT)
{
    __shared__ float ts[32][33];
    const int bx = blockIdx.x;
    const int t  = threadIdx.x;

    if (bx < 12288) {
        const int z = bx >> 12;
        const float* src = (z == 0) ? Xq : (z == 1) ? Xk : Xv;
        const size_t i4 = (size_t)(bx & 4095) * 256 + t;
        float4 v = ((const float4*)src)[i4];
        ushort4 o;
        o.x = f2bf(v.x); o.y = f2bf(v.y); o.z = f2bf(v.z); o.w = f2bf(v.w);
        ((ushort4*)(XB + (size_t)z * 4194304))[i4] = o;
    } else if (bx < 16384) {
        const int idx = bx - 12288;
        const int z   = idx >> 10;
        const int rem = idx & 1023;
        const float* W = (z == 0) ? w0 : (z == 1) ? w1 : (z == 2) ? w2 : w3;
        unsigned short* Wt = WtB + (size_t)z * DD;
        const int n0 = (rem & 31) * 32;
        const int k0 = (rem >> 5) * 32;
        const int r  = t >> 3;
        const int c  = (t & 7) * 4;
        float4 v = *(const float4*)&W[(size_t)(k0 + r) * DMODEL + n0 + c];
        ts[r][c + 0] = v.x; ts[r][c + 1] = v.y;
        ts[r][c + 2] = v.z; ts[r][c + 3] = v.w;
        __syncthreads();
        ushort4 o;
        o.x = f2bf(ts[c + 0][r]); o.y = f2bf(ts[c + 1][r]);
        o.z = f2bf(ts[c + 2][r]); o.w = f2bf(ts[c + 3][r]);
        *(ushort4*)&Wt[(size_t)(n0 + r) * DMODEL + k0 + c] = o;
    } else {
        const int lane = t & 63;
        const size_t wbase = (size_t)(bx - 16384) * 4 + (t >> 6);
#pragma unroll
        for (int it = 0; it < 8; ++it) {
            const size_t wid = wbase + (size_t)it * 16384;   // < 131072
            const int mv = mask[wid * 64 + lane];
            const unsigned long long bits = __ballot(mv != 0);
            if (lane == 0) {
                const int b   = (int)(wid >> 16);
                const int rem = (int)(wid & 65535);
                const int row = rem >> 5;
                const int wd  = rem & 31;
                MWT[((size_t)b * 32 + wd) * L_SEQ + row] = bits;
            }
        }
    }
}

// ---------------------------------------------------------------------------
// QKV GEMM (unchanged)
// ---------------------------------------------------------------------------
__global__ __launch_bounds__(256)
void gemm_qkv(const unsigned short* __restrict__ XB,
              const unsigned short* __restrict__ WtB,
              unsigned short* __restrict__ QKV)
{
    __shared__ __align__(16) unsigned short SMEM[16384];   // 32 KB

    const int t    = threadIdx.x;
    const int w    = t >> 6;
    const int lane = t & 63;

    const int bid   = blockIdx.x;
    const int xcd   = bid & 7;
    const int idx   = bid >> 3;           // 0..95
    const int pair  = xcd * 12 + (idx >> 3);
    const int n0    = (idx & 7) * 128;
    const int m0    = (pair & 31) * 128;
    const int z     = pair >> 5;

    const unsigned short* A = XB  + (size_t)z * ((size_t)MROWS * DMODEL);
    const unsigned short* B = WtB + (size_t)z * DD;

    const int srow = lane >> 2;
    const int sc4  = (lane & 3) ^ (srow & 3);

    const unsigned short* ag[2];
    const unsigned short* bg[2];
    int lao[2], lbo[2];
#pragma unroll
    for (int g = 0; g < 2; ++g) {
        const int R = w * 32 + g * 16;
        ag[g] = A + (size_t)(m0 + R + srow) * DMODEL + sc4 * 8;
        bg[g] = B + (size_t)(n0 + R + srow) * DMODEL + sc4 * 8;
        lao[g] = R * 32;
        lbo[g] = R * 32;
    }

    const int ml = lane & 15;
    const int q  = lane >> 4;
    const int wm = (w >> 1) * 64;
    const int wn = (w & 1) * 64;

    const f32x4 z4 = {0.f, 0.f, 0.f, 0.f};
    f32x4 acc[4][4];
#pragma unroll
    for (int i = 0; i < 4; ++i)
#pragma unroll
        for (int j = 0; j < 4; ++j) acc[i][j] = z4;

#pragma unroll
    for (int g = 0; g < 2; ++g) {
        gll16(ag[g], &SMEM[lao[g]]);
        gll16(bg[g], &SMEM[8192 + lbo[g]]);
    }

    for (int j = 0; j < 32; ++j) {
        const int cur = j & 1;
        __syncthreads();
        if (j < 31) {
            const int kt = (j + 1) * 32;
            const int nb = (cur ^ 1) * 4096;
#pragma unroll
            for (int g = 0; g < 2; ++g) {
                gll16(ag[g] + kt, &SMEM[nb + lao[g]]);
                gll16(bg[g] + kt, &SMEM[8192 + nb + lbo[g]]);
            }
        }
        const unsigned short* As = &SMEM[cur * 4096];
        const unsigned short* Bs = &SMEM[8192 + cur * 4096];
        short8 av[4], bv[4];
#pragma unroll
        for (int mt = 0; mt < 4; ++mt)
            av[mt] = *(const short8*)
                &As[(wm + mt * 16 + ml) * 32 + ((q ^ (ml & 3)) * 8)];
#pragma unroll
        for (int nt = 0; nt < 4; ++nt)
            bv[nt] = *(const short8*)
                &Bs[(wn + nt * 16 + ml) * 32 + ((q ^ (ml & 3)) * 8)];
#pragma unroll
        for (int mt = 0; mt < 4; ++mt)
#pragma unroll
            for (int nt = 0; nt < 4; ++nt)
                acc[mt][nt] = __builtin_amdgcn_mfma_f32_16x16x32_bf16(
                    av[mt], bv[nt], acc[mt][nt], 0, 0, 0);
    }

    unsigned short* O = QKV + (size_t)z * ((size_t)MROWS * DMODEL);
    __syncthreads();                     // K-loop reads done; reuse SMEM
    unsigned short* Ts = SMEM;           // [128][128] bf16 = 32 KB

    if (z == 2) {
        // V^T: stage transposed [tcol=n][trow=m] (swizzled), wide stores
#pragma unroll
        for (int mt = 0; mt < 4; ++mt) {
            const int trow0 = wm + mt * 16 + q * 4;
            const int ch    = trow0 >> 3;
#pragma unroll
            for (int nt = 0; nt < 4; ++nt) {
                const int tcol = wn + nt * 16 + ml;
                const int pc   = (ch & 8) | ((ch & 7) ^ (tcol & 7));
                ushort4 pv;
                pv.x = f2bf(acc[mt][nt][0]); pv.y = f2bf(acc[mt][nt][1]);
                pv.z = f2bf(acc[mt][nt][2]); pv.w = f2bf(acc[mt][nt][3]);
                *(ushort4*)&Ts[tcol * 128 + pc * 8 + (trow0 & 7)] = pv;
            }
        }
        __syncthreads();
        const int bb = m0 >> 11;
        const int l0 = (m0 & (L_SEQ - 1)) + (t & 15) * 8;
        const int cr = t & 15;
#pragma unroll
        for (int it = 0; it < 8; ++it) {
            const int tcol = (t >> 4) + 16 * it;
            const int pc   = (cr & 8) | ((cr & 7) ^ (tcol & 7));
            short8 vv = *(const short8*)&Ts[tcol * 128 + pc * 8];
            const int n  = n0 + tcol;
            const int hh = n >> 6;
            const int dk = n & (DKH - 1);
            *(short8*)&O[((size_t)(bb * NH + hh) * DKH + dk) * L_SEQ + l0] = vv;
        }
    } else {
        // Q/K: stage untransposed [m][n], then short8 stores along dk
        const float qs = (z == 0) ? QSCALE : 1.0f;
#pragma unroll
        for (int mt = 0; mt < 4; ++mt) {
            const int row0 = wm + mt * 16 + q * 4;
#pragma unroll
            for (int nt = 0; nt < 4; ++nt) {
                const int col = wn + nt * 16 + ml;
#pragma unroll
                for (int r = 0; r < 4; ++r)
                    Ts[(row0 + r) * 128 + col] = f2bf(acc[mt][nt][r] * qs);
            }
        }
        __syncthreads();
        const int mloc = t >> 3;              // 0..31 (+32*pass)
        const int c0   = t & 7;               // chunk 0..7 (+8*half)
#pragma unroll
        for (int pass = 0; pass < 4; ++pass) {
#pragma unroll
            for (int half = 0; half < 2; ++half) {
                const int m = mloc + 32 * pass;
                const int c = c0 + 8 * half;
                short8 v = *(const short8*)&Ts[m * 128 + c * 8];
                const int row = m0 + m;
                const int bb  = row >> 11;
                const int l   = row & (L_SEQ - 1);
                const int n   = n0 + c * 8;
                const int hh  = n >> 6;
                const int dk  = n & (DKH - 1);
                *(short8*)&O[(((size_t)(bb * NH + hh) * L_SEQ + l) << 6) + dk] = v;
            }
        }
    }
}

// ---------------------------------------------------------------------------
// Output GEMM (unchanged)
// ---------------------------------------------------------------------------
__global__ __launch_bounds__(256)
void gemm_out(const unsigned short* __restrict__ OB,
              const unsigned short* __restrict__ Wt,
              float* __restrict__ out)
{
    __shared__ __align__(16) unsigned short As[2][2048];
    __shared__ __align__(16) unsigned short Bs[2][4096];

    const int t    = threadIdx.x;
    const int w    = t >> 6;
    const int lane = t & 63;

    const int bid = blockIdx.x;
    const int xcd = bid & 7;
    const int idx = bid >> 3;             // 0..63
    const int n0  = (idx & 7) * 128;
    const int m0  = (xcd * 8 + (idx >> 3)) * 64;

    const int srow = lane >> 2;
    const int sc4  = (lane & 3) ^ (srow & 3);

    const unsigned short* ag =
        OB + (size_t)(m0 + w * 16 + srow) * DMODEL + sc4 * 8;
    const unsigned short* bg[2];
    int lbo[2];
#pragma unroll
    for (int g = 0; g < 2; ++g) {
        const int R = w * 32 + g * 16;
        bg[g] = Wt + (size_t)(n0 + R + srow) * DMODEL + sc4 * 8;
        lbo[g] = R * 32;
    }
    const int lao = (w * 16) * 32;

    const int ml = lane & 15;
    const int q  = lane >> 4;
    const int wm = (w >> 1) * 32;
    const int wn = (w & 1) * 64;

    const f32x4 z4 = {0.f, 0.f, 0.f, 0.f};
    f32x4 acc[2][4];
#pragma unroll
    for (int i = 0; i < 2; ++i)
#pragma unroll
        for (int j = 0; j < 4; ++j) acc[i][j] = z4;

    gll16(ag, &As[0][lao]);
#pragma unroll
    for (int g = 0; g < 2; ++g) gll16(bg[g], &Bs[0][lbo[g]]);

    for (int j = 0; j < 32; ++j) {
        const int cur = j & 1;
        __syncthreads();
        if (j < 31) {
            const int kt = (j + 1) * 32;
            gll16(ag + kt, &As[cur ^ 1][lao]);
#pragma unroll
            for (int g = 0; g < 2; ++g)
                gll16(bg[g] + kt, &Bs[cur ^ 1][lbo[g]]);
        }
        short8 av[2], bv[4];
#pragma unroll
        for (int mt = 0; mt < 2; ++mt)
            av[mt] = *(const short8*)
                &As[cur][(wm + mt * 16 + ml) * 32 + ((q ^ (ml & 3)) * 8)];
#pragma unroll
        for (int nt = 0; nt < 4; ++nt)
            bv[nt] = *(const short8*)
                &Bs[cur][(wn + nt * 16 + ml) * 32 + ((q ^ (ml & 3)) * 8)];
#pragma unroll
        for (int mt = 0; mt < 2; ++mt)
#pragma unroll
            for (int nt = 0; nt < 4; ++nt)
                acc[mt][nt] = __builtin_amdgcn_mfma_f32_16x16x32_bf16(
                    av[mt], bv[nt], acc[mt][nt], 0, 0, 0);
    }

#pragma unroll
    for (int mt = 0; mt < 2; ++mt) {
        const int gr0 = m0 + wm + mt * 16 + q * 4;
#pragma unroll
        for (int nt = 0; nt < 4; ++nt) {
            const int col = n0 + wn + nt * 16 + ml;
#pragma unroll
            for (int r = 0; r < 4; ++r)
                out[(size_t)(gr0 + r) * DMODEL + col] = acc[mt][nt][r];
        }
    }
}

// ---------------------------------------------------------------------------
// MFMA flash attention — 512-thread blocks (8 waves x 16 q-rows, Q-tile 128):
// R2's dbuf + single-barrier + reg-staged pipeline kept verbatim, but with
// 16 waves/CU (4/SIMD) instead of 8/CU — the latency-bound regime (MFMA 20%,
// VALU 45%, no pipe saturated at 2 waves/SIMD) needs more resident waves.
// Each wave stages 8 K-rows + 8 V^T-rows (one short8 pair per iter).
// LDS 50 KB, grid 512 = 2 blocks/CU.
// ---------------------------------------------------------------------------
__global__ __launch_bounds__(512, 4)
void attn_mfma(const unsigned short* __restrict__ Qb,
               const unsigned short* __restrict__ Kb,
               const unsigned short* __restrict__ Vtb,
               const unsigned long long* __restrict__ MWT,
               unsigned short* __restrict__ OB)
{
    __shared__ __align__(16) unsigned short Ks[2][64 * 64];    // 16 KB
    __shared__ __align__(16) unsigned short Vts[2][64 * 64];   // 16 KB
    __shared__ __align__(16) unsigned short Ps[8][16 * 64];    // 16 KB
    __shared__ __align__(16) unsigned long long MskL[2][128];  //  2 KB

    const int t    = threadIdx.x;
    const int w    = t >> 6;               // 0..7
    const int lane = t & 63;
    const int ml   = lane & 15;
    const int quad = lane >> 4;

    // 512 blocks: xcd = bid&7; 4 (b,h) pairs per XCD x 16 q-tiles
    const int bid = blockIdx.x;
    const int xcd = bid & 7;
    const int idx = bid >> 3;              // 0..63
    const int p   = xcd * 4 + (idx >> 4);  // (b,h) 0..31
    const int jq  = idx & 15;
    const int h   = p & 15;
    const int b   = p >> 4;
    const int q0  = jq * 128;

    const size_t hoff = (size_t)(b * NH + h) * L_SEQ * DKH;
    const unsigned short* Qh  = Qb  + hoff;
    const unsigned short* Kh  = Kb  + hoff;
    const unsigned short* Vth = Vtb + hoff;     // [64][L_SEQ]

    const int srow = lane >> 3;            // 0..7
    const int sc   = (lane & 7) ^ srow;

    // ---- stage Q (128x64 = 16 KB) into the Ks overlay (both buffers) ----
    unsigned short* QL = &Ks[0][0];
    gll16(Qh + (size_t)(q0 + w * 16 + srow) * DKH + sc * 8,
          &QL[(w * 16) * 64]);
    gll16(Qh + (size_t)(q0 + w * 16 + 8 + srow) * DKH + sc * 8,
          &QL[(w * 16 + 8) * 64]);

    // ---- K/V tile 0 into regs (one 8-row slab per wave) ----
    const unsigned short* kg = Kh + (size_t)(w * 8 + srow) * DKH + sc * 8;
    const unsigned short* vg = Vth + (size_t)(w * 8 + srow) * L_SEQ + sc * 8;

    short8 kr = *(const short8*)kg;  kg += 64 * DKH;
    short8 vr = *(const short8*)vg;  vg += 64;

    const unsigned long long* mg = MWT + (size_t)b * 32 * L_SEQ + q0 + t;
    unsigned long long m_pf = 0;
    if (t < 128) m_pf = mg[0];

    __syncthreads();                       // Q visible (vmcnt drained)

    short8 qf[2];
#pragma unroll
    for (int s = 0; s < 2; ++s)
        qf[s] = *(const short8*)
            &QL[(w * 16 + ml) * 64 + (((s * 4 + quad) ^ (ml & 7)) * 8)];

    __syncthreads();                       // all waves read Q; Ks reusable

    // ---- write tile 0 -> buf0; issue tile 1 ----
    *(short8*)&Ks[0][(w * 8) * 64 + lane * 8]  = kr;
    *(short8*)&Vts[0][(w * 8) * 64 + lane * 8] = vr;
    if (t < 128) MskL[0][t] = m_pf;

    kr = *(const short8*)kg;  kg += 64 * DKH;
    vr = *(const short8*)vg;  vg += 64;
    if (t < 128) m_pf = mg[L_SEQ];

    f32x4 oacc[4];
    const f32x4 z4 = {0.f, 0.f, 0.f, 0.f};
#pragma unroll
    for (int dt = 0; dt < 4; ++dt) oacc[dt] = z4;
    float l_i = 0.f;

    __syncthreads();                       // tile 0 visible

    for (int j = 0; j < 32; ++j) {
        const int cur = j & 1;
        if (j < 31) {
            const int nxt = cur ^ 1;
            // write tile j+1 (regs issued at iter j-1; latency hidden)
            *(short8*)&Ks[nxt][(w * 8) * 64 + lane * 8]  = kr;
            *(short8*)&Vts[nxt][(w * 8) * 64 + lane * 8] = vr;
            if (t < 128) MskL[nxt][t] = m_pf;
            if (j < 30) {
                // issue tile j+2 loads; drain at iter j+1's ds_write
                kr = *(const short8*)kg;  kg += 64 * DKH;
                vr = *(const short8*)vg;  vg += 64;
                if (t < 128) m_pf = mg[(size_t)(j + 2) * L_SEQ];
            }
        }

        // ---- QK^T (swapped: lane ml holds q-row, quads hold k-slices) ----
        f32x4 sacc[4];
#pragma unroll
        for (int kt = 0; kt < 4; ++kt) sacc[kt] = z4;
#pragma unroll
        for (int s = 0; s < 2; ++s) {
            short8 kf[4];
#pragma unroll
            for (int kt = 0; kt < 4; ++kt)
                kf[kt] = *(const short8*)
                    &Ks[cur][(kt * 16 + ml) * 64 +
                             (((s * 4 + quad) ^ (ml & 7)) * 8)];
#pragma unroll
            for (int kt = 0; kt < 4; ++kt)
                sacc[kt] = __builtin_amdgcn_mfma_f32_16x16x32_bf16(
                    kf[kt], qf[s], sacc[kt], 0, 0, 0);
        }

        // ---- masked softmax numerators ----
        const unsigned long long wq = MskL[cur][w * 16 + ml] >> (quad * 4);
        const unsigned mlo = (unsigned)wq;
        const unsigned mhi = (unsigned)(wq >> 32);
        float rs = 0.f;
        float pr[4][4];
#pragma unroll
        for (int kt = 0; kt < 4; ++kt) {
            const unsigned word = (kt < 2) ? mlo : mhi;
            const int base = (kt & 1) * 16;
#pragma unroll
            for (int r = 0; r < 4; ++r) {
                const float mf = (float)((word >> (base + r)) & 1u);
                const float e  = fexp2(sacc[kt][r] * mf);
                pr[kt][r] = e;
                rs += e;
            }
        }
        rs += __shfl_xor(rs, 16);
        rs += __shfl_xor(rs, 32);
        l_i += rs;
#pragma unroll
        for (int kt = 0; kt < 4; ++kt) {
            uint2 pk;
            pk.x = pk_bf16(pr[kt][0], pr[kt][1]);
            pk.y = pk_bf16(pr[kt][2], pr[kt][3]);
            const int cp = (kt * 2 + (quad >> 1)) ^ (ml & 7);
            *(uint2*)&Ps[w][ml * 64 + cp * 8 + (quad & 1) * 4] = pk;
        }

        // ---- PV ----
#pragma unroll
        for (int s = 0; s < 2; ++s) {
            const short8 pf = *(const short8*)
                &Ps[w][ml * 64 + (((s * 4 + quad) ^ (ml & 7)) * 8)];
#pragma unroll
            for (int dt = 0; dt < 4; ++dt) {
                const short8 vf = *(const short8*)
                    &Vts[cur][(dt * 16 + ml) * 64 +
                              (((s * 4 + quad) ^ (ml & 7)) * 8)];
                oacc[dt] = __builtin_amdgcn_mfma_f32_16x16x32_bf16(
                    vf, pf, oacc[dt], 0, 0, 0);
            }
        }

        __syncthreads();                   // single barrier per iteration
    }

    const float inv = 1.0f / l_i;
    const int qrow = q0 + w * 16 + ml;
#pragma unroll
    for (int dt = 0; dt < 4; ++dt) {
        ushort4 o4;
        o4.x = f2bf(oacc[dt][0] * inv);
        o4.y = f2bf(oacc[dt][1] * inv);
        o4.z = f2bf(oacc[dt][2] * inv);
        o4.w = f2bf(oacc[dt][3] * inv);
        *(ushort4*)&OB[(size_t)(b * L_SEQ + qrow) * DMODEL + h * DKH +
                       dt * 16 + quad * 4] = o4;
    }
}

// ---------------------------------------------------------------------------
extern "C" void kernel_launch(void* const* d_in, const int* in_sizes, int n_in,
                              void* d_out, int out_size, void* d_ws, size_t ws_size,
                              hipStream_t stream)
{
    (void)in_sizes; (void)n_in; (void)out_size; (void)ws_size;

    const float* Xq   = (const float*)d_in[0];
    const float* Xk   = (const float*)d_in[1];
    const float* Xv   = (const float*)d_in[2];
    const float* Wq   = (const float*)d_in[3];
    const float* Wk   = (const float*)d_in[4];
    const float* Wv   = (const float*)d_in[5];
    const float* Wo   = (const float*)d_in[6];
    const int*   mask = (const int*)d_in[7];
    float* out = (float*)d_out;

    char* base = (char*)d_ws;
    unsigned short*     XB  = (unsigned short*)base;                 // 24 MB
    unsigned short*     WtB = (unsigned short*)(base + (24u << 20)); //  8 MB
    unsigned short*     QKV = (unsigned short*)(base + (32u << 20)); // 24 MB
    unsigned short*     OB  = (unsigned short*)(base + (56u << 20)); //  8 MB
    unsigned long long* MWT = (unsigned long long*)(base + (64u << 20)); // 1 MB

    const size_t tsz = (size_t)MROWS * DMODEL;   // 4,194,304

    prep<<<dim3(20480), 256, 0, stream>>>(
        Xq, Xk, Xv, Wq, Wk, Wv, Wo, mask, XB, WtB, MWT);

    gemm_qkv<<<dim3(768), 256, 0, stream>>>(XB, WtB, QKV);

    attn_mfma<<<dim3(512), 512, 0, stream>>>(
        QKV, QKV + tsz, QKV + 2 * tsz, MWT, OB);

    gemm_out<<<dim3(512), 256, 0, stream>>>(OB, WtB + 3 * (size_t)DD, out);
}